// Round 4
// baseline (135.543 us; speedup 1.0000x reference)
//
#include <hip/hip_runtime.h>

#define CH 30
#define CELLS 49
#define ROWF 1470          // floats per batch row
#define NPAIR 735          // float2 pairs per row
#define NQ4 735            // float4 quads per 2-row region
#define WPB 4              // waves per block
#define RPBLK 4            // rows per block = 2 regions x 2 rows
#define HITS 6             // quad-stripes per wave (half of a region)
#define DEPTH 3            // rotating prefetch depth (24 staging VGPRs)

__device__ __forceinline__ float waveReduce(float v) {
    #pragma unroll
    for (int o = 32; o > 0; o >>= 1) v += __shfl_xor(v, o, 64);
    return v;
}

// Two waves share one 2-row (float4-aligned) region in alternating 64-quad
// stripes. Depth-3 rotating prefetch (vs R3's depth-2) with launch_bounds
// (256,6): cap 85 VGPR -- room to avoid spills (R3 risk at cap 64) while
// allowing 6 waves/SIMD. NEW: obj-cell box channels (ch<10) are captured
// into LDS during the stream consume, so the box/IoU tail reads LDS only
// (R3 re-read ~30 scattered global dwords per lane through L2/HBM latency
// chains). One block barrier publishes the cross-wave captures.
__global__ __launch_bounds__(256, 6) void yolo_main(const float* __restrict__ pred,
                                                    const float* __restrict__ targ,
                                                    float* __restrict__ ws, int B,
                                                    int NB) {
    const int w = threadIdx.x >> 6;
    const int lane = threadIdx.x & 63;
    const int h = w & 1;                         // half (stripe parity / box row)
    const int g = w >> 1;                        // region within block
    const int r0 = blockIdx.x * RPBLK + g * 2;

    __shared__ float boxRaw[2][2][2][CELLS][10]; // [region][P=0/T=1][row][cell][ch]
    __shared__ float4 boxS[WPB][2 * CELLS];      // pred boxes xyxy (broadcast)
    __shared__ int clist[WPB][CELLS];
    __shared__ float sred[WPB][3];

    float cls = 0.f, objc = 0.f, coord = 0.f;
    unsigned long long m[2] = {0ull, 0ull};
    int nrows = 0;

    const float* P = pred + (size_t)r0 * ROWF;
    const float* T = targ + (size_t)r0 * ROWF;

    if (r0 < B) {                                // wave-uniform
        nrows = (B - r0) >= 2 ? 2 : 1;

        if (nrows == 2) {
            const float4* P4 = (const float4*)P;
            const float4* T4 = (const float4*)T;

            // ---- conf gathers first (ballot dependency chain) ----
            const int cl = lane < CELLS ? lane : CELLS - 1;
            const float conf0 = T[cl * CH + 4];
            const float conf1 = T[ROWF + cl * CH + 4];

            // ---- pipeline prologue: issue stripes 0..DEPTH-1 of this half ----
            float4 pv[DEPTH], tv[DEPTH];
            #pragma unroll
            for (int s = 0; s < DEPTH; ++s) {
                const int q = lane + (2 * s + h) * 64;
                const int qc = q < NQ4 ? q : NQ4 - 1;
                pv[s] = P4[qc];
                tv[s] = T4[qc];
            }

            m[0] = __ballot((lane < CELLS) && (conf0 > 0.f));
            m[1] = __ballot((lane < CELLS) && (conf1 > 0.f));

            // ---- depth-3 rotating pipeline over this wave's 6 stripes ----
            #pragma unroll
            for (int it = 0; it < HITS; ++it) {
                const int slot = it % DEPTH;      // static after full unroll
                const float4 pa = pv[slot];
                const float4 ta = tv[slot];
                if (it + DEPTH < HITS) {
                    const int qn = lane + (2 * (it + DEPTH) + h) * 64;
                    const int qc = qn < NQ4 ? qn : NQ4 - 1;
                    pv[slot] = P4[qc];
                    tv[slot] = T4[qc];
                }
                const int qq = lane + (2 * it + h) * 64;
                const bool valid = qq < NQ4;
                #pragma unroll
                for (int k = 0; k < 2; ++k) {
                    const int p = 2 * qq + k;            // pair idx in 2-row stream
                    const int row = p >= NPAIR ? 1 : 0;
                    const int pr = p - row * NPAIR;      // pair idx within row
                    const int cell = (pr * 17477) >> 18; // pr/15 (valid to 767)
                    const int ch0 = 2 * (pr - cell * 15);
                    const int bit = (int)((m[row] >> cell) & 1ull); // 0 for cell>=49
                    const float wobj = (float)bit;
                    const float px = k ? pa.z : pa.x;
                    const float py = k ? pa.w : pa.y;
                    const float tx = k ? ta.z : ta.x;
                    const float ty = k ? ta.w : ta.y;
                    const float dx = px - tx, dy = py - ty;
                    // class loss: channels 10..29, obj cells only
                    cls += (valid && ch0 >= 10) ? wobj * (dx * dx + dy * dy) : 0.f;
                    // noobj conf loss (x0.5 folded): ch4 (.x) + ch9 (.y)
                    const float nn = (ch0 == 4 ? dx * dx : 0.f)
                                   + (ch0 == 8 ? dy * dy : 0.f);
                    objc += valid ? 0.5f * (1.f - wobj) * nn : 0.f;
                    // capture obj-cell box channels for the LDS-only tail
                    if (valid && bit && ch0 < 10) {
                        float* dp = &boxRaw[g][0][row][cell][ch0];
                        dp[0] = px; dp[1] = py;
                        float* dt = &boxRaw[g][1][row][cell][ch0];
                        dt[0] = tx; dt[1] = ty;
                    }
                }
            }
        } else if (h == 0) {
            // ---- fallback: single trailing row (never hit for B%4==0) ----
            const float2* P2 = (const float2*)P;
            const float2* T2 = (const float2*)T;
            const int cl = lane < CELLS ? lane : CELLS - 1;
            const float conf = T[cl * CH + 4];
            const bool isObj = (lane < CELLS) && (conf > 0.f);
            const unsigned long long mask = __ballot(isObj);
            for (int j = lane; j < NPAIR; j += 64) {
                const float2 pq = P2[j], tq = T2[j];
                const int cell = (j * 17477) >> 18;
                const int ch0 = 2 * (j - cell * 15);
                const float wobj = (float)((mask >> cell) & 1ull);
                const float dx = pq.x - tq.x, dy = pq.y - tq.y;
                cls += (ch0 >= 10) ? wobj * (dx * dx + dy * dy) : 0.f;
                const float nn = (ch0 == 4 ? dx * dx : 0.f)
                               + (ch0 == 8 ? dy * dy : 0.f);
                objc += 0.5f * (1.f - wobj) * nn;
            }
            const int nBox = 2 * __popcll(mask);
            if (nBox) {
                if (isObj) clist[w][__popcll(mask & ((1ull << lane) - 1ull))] = lane;
                for (int e = lane; e < nBox; e += 64) {
                    const int c = clist[w][e >> 1];
                    const float* pb = P + c * CH + (e & 1) * 5;
                    const float cx = pb[0], cy = pb[1], bw = pb[2], bh = pb[3];
                    boxS[w][e] = make_float4(cx - 0.5f * bw, cy - 0.5f * bh,
                                             cx + 0.5f * bw, cy + 0.5f * bh);
                }
                for (int e = lane; e < nBox; e += 64) {
                    const int c = clist[w][e >> 1];
                    const float* tb = T + c * CH + (e & 1) * 5;
                    const float tcx = tb[0], tcy = tb[1], tw = tb[2], th = tb[3];
                    const float tx1 = tcx - 0.5f * tw, ty1 = tcy - 0.5f * th;
                    const float tx2 = tcx + 0.5f * tw, ty2 = tcy + 0.5f * th;
                    const float ta2 = (tx2 - tx1) * (ty2 - ty1);
                    float maxiou = 0.f;
                    for (int i = 0; i < nBox; ++i) {
                        const float4 pb4 = boxS[w][i];
                        const float lx = fmaxf(pb4.x, tx1), ly = fmaxf(pb4.y, ty1);
                        const float rx = fminf(pb4.z, tx2), ry = fminf(pb4.w, ty2);
                        const float iw = fmaxf(rx - lx, 0.f), ih = fmaxf(ry - ly, 0.f);
                        const float inter = iw * ih;
                        const float pa2 = (pb4.z - pb4.x) * (pb4.w - pb4.y);
                        const float un = pa2 + ta2 - inter;
                        const float iou = inter / (un > 0.f ? un : 1.f);
                        maxiou = fmaxf(maxiou, iou);
                    }
                    if (maxiou != 0.f) {
                        const float* pb = P + c * CH + (e & 1) * 5;
                        const float dcx = pb[0] - tcx, dcy = pb[1] - tcy;
                        coord += dcx * dcx + dcy * dcy;
                        const float dw = sqrtf(pb[2]) - sqrtf(tw);
                        const float dh = sqrtf(pb[3]) - sqrtf(th);
                        coord += dw * dw + dh * dh;
                        const float dc = pb[4] - tb[4];
                        objc += dc * dc;
                    }
                }
            }
        }
    }

    // ---- publish cross-wave captures (both waves of a region wrote boxRaw) ----
    __syncthreads();

    if (r0 < B && nrows == 2) {
        // ---- box/IoU phase, LDS-only: this wave handles row h of region g ----
        const unsigned long long mask = m[h];
        const int nBox = 2 * __popcll(mask);
        if (nBox) {                                  // wave-uniform
            const bool isObj = (lane < CELLS) && ((mask >> lane) & 1ull);
            if (isObj) clist[w][__popcll(mask & ((1ull << lane) - 1ull))] = lane;

            for (int e = lane; e < nBox; e += 64) {
                const int c = clist[w][e >> 1];
                const float* pb = &boxRaw[g][0][h][c][(e & 1) * 5];
                const float cx = pb[0], cy = pb[1], bw = pb[2], bh = pb[3];
                boxS[w][e] = make_float4(cx - 0.5f * bw, cy - 0.5f * bh,
                                         cx + 0.5f * bw, cy + 0.5f * bh);
            }

            for (int e = lane; e < nBox; e += 64) {
                const int c = clist[w][e >> 1];
                const float* tb = &boxRaw[g][1][h][c][(e & 1) * 5];
                const float tcx = tb[0], tcy = tb[1], tw = tb[2], th = tb[3];
                const float tx1 = tcx - 0.5f * tw, ty1 = tcy - 0.5f * th;
                const float tx2 = tcx + 0.5f * tw, ty2 = tcy + 0.5f * th;
                const float ta2 = (tx2 - tx1) * (ty2 - ty1);
                float maxiou = 0.f;
                for (int i = 0; i < nBox; ++i) {
                    const float4 pb4 = boxS[w][i];   // uniform addr = broadcast
                    const float lx = fmaxf(pb4.x, tx1), ly = fmaxf(pb4.y, ty1);
                    const float rx = fminf(pb4.z, tx2), ry = fminf(pb4.w, ty2);
                    const float iw = fmaxf(rx - lx, 0.f), ih = fmaxf(ry - ly, 0.f);
                    const float inter = iw * ih;
                    const float pa2 = (pb4.z - pb4.x) * (pb4.w - pb4.y);
                    const float un = pa2 + ta2 - inter;
                    const float iou = inter / (un > 0.f ? un : 1.f);
                    maxiou = fmaxf(maxiou, iou);
                }
                if (maxiou != 0.f) {                 // cmask
                    const float* pb = &boxRaw[g][0][h][c][(e & 1) * 5];
                    const float dcx = pb[0] - tcx, dcy = pb[1] - tcy;
                    coord += dcx * dcx + dcy * dcy;
                    const float dw = sqrtf(pb[2]) - sqrtf(tw);
                    const float dh = sqrtf(pb[3]) - sqrtf(th);
                    coord += dw * dw + dh * dh;
                    const float dc = pb[4] - tb[4];
                    objc += dc * dc;
                }
            }
        }
    }

    // ---- wave reduce, then block reduce (one barrier), one triple per block ----
    cls = waveReduce(cls); objc = waveReduce(objc); coord = waveReduce(coord);
    if (lane == 0) { sred[w][0] = cls; sred[w][1] = objc; sred[w][2] = coord; }
    __syncthreads();
    if (threadIdx.x == 0) {
        float C = 0.f, O = 0.f, X = 0.f;
        #pragma unroll
        for (int k = 0; k < WPB; ++k) { C += sred[k][0]; O += sred[k][1]; X += sred[k][2]; }
        ws[blockIdx.x] = C;
        ws[NB + blockIdx.x] = O;
        ws[2 * NB + blockIdx.x] = X;
    }
}

__global__ __launch_bounds__(1024) void yolo_reduce(const float* __restrict__ ws,
                                                    float* __restrict__ out,
                                                    int NB, float invB) {
    const int tid = threadIdx.x;
    const int w = tid >> 6, lane = tid & 63;
    float c = 0.f, o = 0.f, x = 0.f;
    for (int i = tid; i < NB; i += 1024) {
        c += ws[i];
        o += ws[NB + i];
        x += ws[2 * NB + i];
    }
    c = waveReduce(c); o = waveReduce(o); x = waveReduce(x);
    __shared__ float sred[16][3];
    if (lane == 0) { sred[w][0] = c; sred[w][1] = o; sred[w][2] = x; }
    __syncthreads();
    if (tid == 0) {
        float C = 0.f, O = 0.f, X = 0.f;
        #pragma unroll
        for (int k = 0; k < 16; ++k) { C += sred[k][0]; O += sred[k][1]; X += sred[k][2]; }
        const float bcls = C * invB;
        const float bobj = O * invB;          // noobj*0.5 folded upstream
        const float bcoord = X * 5.0f * invB; // COORD_LAMBDA
        out[0] = bcls + bobj + bcoord;
        out[1] = bcls;
        out[2] = bobj;
        out[3] = bcoord;
    }
}

extern "C" void kernel_launch(void* const* d_in, const int* in_sizes, int n_in,
                              void* d_out, int out_size, void* d_ws, size_t ws_size,
                              hipStream_t stream) {
    const float* pred = (const float*)d_in[0];
    const float* targ = (const float*)d_in[1];
    float* ws = (float*)d_ws;
    float* out = (float*)d_out;
    const int B = in_sizes[0] / ROWF;
    const int NB = (B + RPBLK - 1) / RPBLK;

    yolo_main<<<NB, 256, 0, stream>>>(pred, targ, ws, B, NB);
    yolo_reduce<<<1, 1024, 0, stream>>>(ws, out, NB, 1.0f / (float)B);
}

// Round 5
// 126.220 us; speedup vs baseline: 1.0739x; 1.0739x over previous
//
#include <hip/hip_runtime.h>

#define CH 30
#define CELLS 49
#define ROWF 1470          // floats per batch row
#define WPB 4              // waves per block, one wave per row

__device__ __forceinline__ float waveReduce(float v) {
    #pragma unroll
    for (int o = 32; o > 0; o >>= 1) v += __shfl_xor(v, o, 64);
    return v;
}

// Sparse-read formulation (R5). Dataflow fact from the reference: noobj cells
// (~80%) contribute ONLY channels 4 and 9; coord/obj-conf/class are all masked
// to obj cells. So instead of streaming all 96 MB with per-element cell/chan/
// mask math (R1-R4: issue-bound at ~35-47us, VALUBusy*dur >> useful work),
// read exactly what the math uses:
//   phase 1: 4x 49-lane conf gathers (p4,p9,t4,t9) -> ballot -> noobj loss
//   phase 2: class loss, obj cells only (nObj*20 elements, lane-distributed)
//   phase 3: R3's proven box/IoU tail (reads are L1-warm: box+class bytes
//            share 64B lines with the phase-1/2 gathers)
// One wave per row, no mid-kernel barrier (clist/boxS are per-wave slices),
// single barrier for the block partial reduce.
__global__ __launch_bounds__(256) void yolo_main(const float* __restrict__ pred,
                                                 const float* __restrict__ targ,
                                                 float* __restrict__ ws, int B,
                                                 int NB) {
    const int w = threadIdx.x >> 6;
    const int lane = threadIdx.x & 63;
    const int r = blockIdx.x * WPB + w;

    __shared__ float4 boxS[WPB][2 * CELLS];  // pred boxes xyxy (broadcast reads)
    __shared__ int clist[WPB][CELLS];
    __shared__ float sred[WPB][3];

    float cls = 0.f, objc = 0.f, coord = 0.f;

    if (r < B) {                             // wave-uniform
        const float* P = pred + (size_t)r * ROWF;
        const float* T = targ + (size_t)r * ROWF;

        // ---- phase 1: conf gathers (all 4 issued together, independent) ----
        const int cl = lane < CELLS ? lane : CELLS - 1;
        const float t4 = T[cl * CH + 4];
        const float p4 = P[cl * CH + 4];
        const float t9 = T[cl * CH + 9];
        const float p9 = P[cl * CH + 9];

        const bool act = lane < CELLS;
        const bool isObj = act && (t4 > 0.f);
        const unsigned long long m = __ballot(isObj);

        // noobj conf loss (NOOBJ_LAMBDA=0.5 folded): exact reference terms
        if (act && !isObj) {
            const float d4 = p4 - t4, d9 = p9 - t9;
            objc += 0.5f * (d4 * d4 + d9 * d9);
        }

        const int nObj = __popcll(m);
        if (isObj) clist[w][__popcll(m & ((1ull << lane) - 1ull))] = lane;

        if (nObj) {                          // wave-uniform
            // ---- phase 2: class loss over obj cells (20 chans per cell) ----
            const int nCls = nObj * 20;      // <= 980
            for (int base = 0; base < nCls; base += 64) {
                const int idx = base + lane;
                if (idx < nCls) {
                    const int cc = (idx * 3277) >> 16;   // idx/20, idx<16384
                    const int ch = 10 + (idx - cc * 20);
                    const int c = clist[w][cc];
                    const float dv = P[c * CH + ch] - T[c * CH + ch];
                    cls += dv * dv;
                }
            }

            // ---- phase 3: box/IoU tail (R3-verbatim; reads L1-warm) ----
            const int nBox = 2 * nObj;
            for (int e = lane; e < nBox; e += 64) {
                const int c = clist[w][e >> 1];
                const float* pb = P + c * CH + (e & 1) * 5;
                const float cx = pb[0], cy = pb[1], bw = pb[2], bh = pb[3];
                boxS[w][e] = make_float4(cx - 0.5f * bw, cy - 0.5f * bh,
                                         cx + 0.5f * bw, cy + 0.5f * bh);
            }

            for (int e = lane; e < nBox; e += 64) {
                const int c = clist[w][e >> 1];
                const float* tb = T + c * CH + (e & 1) * 5;
                const float tcx = tb[0], tcy = tb[1], tw = tb[2], th = tb[3];
                const float tx1 = tcx - 0.5f * tw, ty1 = tcy - 0.5f * th;
                const float tx2 = tcx + 0.5f * tw, ty2 = tcy + 0.5f * th;
                const float ta = (tx2 - tx1) * (ty2 - ty1);
                float maxiou = 0.f;
                for (int i = 0; i < nBox; ++i) {
                    const float4 pb4 = boxS[w][i];   // uniform addr = broadcast
                    const float lx = fmaxf(pb4.x, tx1), ly = fmaxf(pb4.y, ty1);
                    const float rx = fminf(pb4.z, tx2), ry = fminf(pb4.w, ty2);
                    const float iw = fmaxf(rx - lx, 0.f), ih = fmaxf(ry - ly, 0.f);
                    const float inter = iw * ih;
                    const float pa = (pb4.z - pb4.x) * (pb4.w - pb4.y);
                    const float un = pa + ta - inter;
                    const float iou = inter / (un > 0.f ? un : 1.f);
                    maxiou = fmaxf(maxiou, iou);
                }
                if (maxiou != 0.f) {                 // cmask
                    const float* pb = P + c * CH + (e & 1) * 5;
                    const float dcx = pb[0] - tcx, dcy = pb[1] - tcy;
                    coord += dcx * dcx + dcy * dcy;
                    const float dw = sqrtf(pb[2]) - sqrtf(tw);
                    const float dh = sqrtf(pb[3]) - sqrtf(th);
                    coord += dw * dw + dh * dh;
                    const float dc = pb[4] - tb[4];  // box conf: ch4 / ch9
                    objc += dc * dc;
                }
            }
        }
    }

    // ---- wave reduce, then block reduce (one barrier), one triple per block ----
    cls = waveReduce(cls); objc = waveReduce(objc); coord = waveReduce(coord);
    if (lane == 0) { sred[w][0] = cls; sred[w][1] = objc; sred[w][2] = coord; }
    __syncthreads();
    if (threadIdx.x == 0) {
        float C = 0.f, O = 0.f, X = 0.f;
        #pragma unroll
        for (int k = 0; k < WPB; ++k) { C += sred[k][0]; O += sred[k][1]; X += sred[k][2]; }
        ws[blockIdx.x] = C;
        ws[NB + blockIdx.x] = O;
        ws[2 * NB + blockIdx.x] = X;
    }
}

__global__ __launch_bounds__(1024) void yolo_reduce(const float* __restrict__ ws,
                                                    float* __restrict__ out,
                                                    int NB, float invB) {
    const int tid = threadIdx.x;
    const int w = tid >> 6, lane = tid & 63;
    float c = 0.f, o = 0.f, x = 0.f;
    for (int i = tid; i < NB; i += 1024) {
        c += ws[i];
        o += ws[NB + i];
        x += ws[2 * NB + i];
    }
    c = waveReduce(c); o = waveReduce(o); x = waveReduce(x);
    __shared__ float sred[16][3];
    if (lane == 0) { sred[w][0] = c; sred[w][1] = o; sred[w][2] = x; }
    __syncthreads();
    if (tid == 0) {
        float C = 0.f, O = 0.f, X = 0.f;
        #pragma unroll
        for (int k = 0; k < 16; ++k) { C += sred[k][0]; O += sred[k][1]; X += sred[k][2]; }
        const float bcls = C * invB;
        const float bobj = O * invB;          // noobj*0.5 folded upstream
        const float bcoord = X * 5.0f * invB; // COORD_LAMBDA
        out[0] = bcls + bobj + bcoord;
        out[1] = bcls;
        out[2] = bobj;
        out[3] = bcoord;
    }
}

extern "C" void kernel_launch(void* const* d_in, const int* in_sizes, int n_in,
                              void* d_out, int out_size, void* d_ws, size_t ws_size,
                              hipStream_t stream) {
    const float* pred = (const float*)d_in[0];
    const float* targ = (const float*)d_in[1];
    float* ws = (float*)d_ws;
    float* out = (float*)d_out;
    const int B = in_sizes[0] / ROWF;
    const int NB = (B + WPB - 1) / WPB;

    yolo_main<<<NB, 256, 0, stream>>>(pred, targ, ws, B, NB);
    yolo_reduce<<<1, 1024, 0, stream>>>(ws, out, NB, 1.0f / (float)B);
}